// Round 2
// baseline (545.606 us; speedup 1.0000x reference)
//
#include <hip/hip_runtime.h>

// Compress70: per-output-pixel gather formulation.
// lv1 [2,64,256,256] f32, lv2 [2,128,128,128] f32, h_index [2,16384] int32
// out = concat(T_lv2 [2,128,128,128], T_lv1 [2,64,256,256]) f32.
//
// Round-2: channel-batched threads (shared index loads, high MLP) and, for
// lv1, 2x2 spatial tiles: the k=6/stride=2 geometry makes output pairs
// (2u,2u+1) share patches, with even-aligned adjacent source columns ->
// aligned float2 gathers serving a 2x2 output block (all-valid-or-none).

#define NC2 8   // channels per thread, lv2 (C=128 -> 16 groups)
#define NC1 4   // channels per thread, lv1 (C=64  -> 16 groups)

__global__ __launch_bounds__(256) void t_lv2_kernel(
    const float* __restrict__ lv2, const int* __restrict__ hidx,
    float* __restrict__ out)
{
    int t  = blockIdx.x * 256 + threadIdx.x;   // 524288 total
    int x  = t & 127;
    int y  = (t >> 7) & 127;
    int cg = (t >> 14) & 15;                   // channel group (16)
    int b  = t >> 18;
    const int*   hb  = hidx + (b << 14);
    const float* src = lv2 + ((b * 128 + cg * NC2) << 14);

    float acc[NC2];
#pragma unroll
    for (int c = 0; c < NC2; ++c) acc[c] = 0.f;

#pragma unroll
    for (int da = -1; da <= 1; ++da) {
        int a = y + da;
        if ((unsigned)a >= 128u) continue;
#pragma unroll
        for (int de = -1; de <= 1; ++de) {
            int e = x + de;
            if ((unsigned)e >= 128u) continue;
            int p  = hb[(a << 7) + e];
            int sr = (p >> 7) - da;
            int sc = (p & 127) - de;
            if ((unsigned)sr < 128u && (unsigned)sc < 128u) {
                int off = (sr << 7) + sc;
#pragma unroll
                for (int c = 0; c < NC2; ++c)
                    acc[c] += src[(c << 14) + off];
            }
        }
    }
    float* o = out + ((b * 128 + cg * NC2) << 14) + (y << 7) + x;
#pragma unroll
    for (int c = 0; c < NC2; ++c) o[c << 14] = acc[c] * (1.f / 9.f);
}

__global__ __launch_bounds__(256) void t_lv1_kernel(
    const float* __restrict__ lv1, const int* __restrict__ hidx,
    float* __restrict__ out)
{
    int t  = blockIdx.x * 256 + threadIdx.x;   // 524288 total
    int ux = t & 127;                          // 2x2 tile coords
    int uy = (t >> 7) & 127;
    int cg = (t >> 14) & 15;                   // channel group (16)
    int b  = t >> 18;
    const int*   hb  = hidx + (b << 14);
    const float* src = lv1 + ((b * 64 + cg * NC1) << 16);

    float acc[NC1][4];                         // [c][v*2+u]
#pragma unroll
    for (int c = 0; c < NC1; ++c)
#pragma unroll
        for (int k = 0; k < 4; ++k) acc[c][k] = 0.f;

#pragma unroll
    for (int ka = 0; ka < 3; ++ka) {
        int jy = uy + 1 - ka;
        if ((unsigned)jy >= 128u) continue;
#pragma unroll
        for (int kb = 0; kb < 3; ++kb) {
            int jx = ux + 1 - kb;
            if ((unsigned)jx >= 128u) continue;
            int p   = hb[(jy << 7) + jx];
            int sr0 = ((p >> 7) << 1) + 2 * ka - 2;   // even; covers rows sr0, sr0+1
            int sc0 = ((p & 127) << 1) + 2 * kb - 2;  // even; covers cols sc0, sc0+1
            if ((unsigned)sr0 < 256u && (unsigned)sc0 < 256u) {
                const float* s = src + (sr0 << 8) + sc0;
#pragma unroll
                for (int c = 0; c < NC1; ++c) {
                    const float* sc_ = s + (c << 16);
                    float2 r0 = *(const float2*)(sc_);        // row v=0 (8B aligned)
                    float2 r1 = *(const float2*)(sc_ + 256);  // row v=1
                    acc[c][0] += r0.x; acc[c][1] += r0.y;
                    acc[c][2] += r1.x; acc[c][3] += r1.y;
                }
            }
        }
    }
    float* o = out + ((b * 64 + cg * NC1) << 16) + (uy << 9) + (ux << 1);
#pragma unroll
    for (int c = 0; c < NC1; ++c) {
        float2 w0 = make_float2(acc[c][0] * (1.f / 9.f), acc[c][1] * (1.f / 9.f));
        float2 w1 = make_float2(acc[c][2] * (1.f / 9.f), acc[c][3] * (1.f / 9.f));
        *(float2*)(o + (c << 16))       = w0;
        *(float2*)(o + (c << 16) + 256) = w1;
    }
}

extern "C" void kernel_launch(void* const* d_in, const int* in_sizes, int n_in,
                              void* d_out, int out_size, void* d_ws, size_t ws_size,
                              hipStream_t stream)
{
    const float* lv1  = (const float*)d_in[0];
    const float* lv2  = (const float*)d_in[1];
    const int*   hidx = (const int*)d_in[2];
    float* out = (float*)d_out;

    const int N2 = 2 * 128 * 128 * 128;   // T_lv2 elements
    // lv2: 524288 threads, lv1: 524288 threads
    t_lv2_kernel<<<2048, 256, 0, stream>>>(lv2, hidx, out);
    t_lv1_kernel<<<2048, 256, 0, stream>>>(lv1, hidx, out + N2);
}

// Round 3
// 150.629 us; speedup vs baseline: 3.6222x; 3.6222x over previous
//
#include <hip/hip_runtime.h>

// Compress70, round 3: channel-contiguous gather.
// Pre-transpose lv2 [2,128,128,128]->ws2 [2][y][x][128c] and
// lv1 [2,64,256,256]->ws1 [2][sy][sx][64c]; then each of the 9 random
// gathers per output pixel is a fully-coalesced 512B/256B wave load
// amortized over ALL channels, instead of one scalar touch per channel.
// Falls back to round-1 scalar-gather kernels if ws_size < 50.3MB.

#define N2ELTS (2*128*128*128)   // 4194304
#define N1ELTS (2*64*256*256)    // 8388608
#define WS_NEED ((size_t)(N2ELTS + N1ELTS) * 4)

// ---------------- transposes ----------------

__global__ __launch_bounds__(256) void transpose2_kernel(
    const float* __restrict__ in, float* __restrict__ out)
{
    __shared__ float tile[128][65];
    int b  = blockIdx.x >> 8;
    int p0 = (blockIdx.x & 255) << 6;          // 64 pixels per tile
    const float* src = in + (long)b * (128 * 16384);
    int pl = threadIdx.x & 63;
    int cb = threadIdx.x >> 6;
#pragma unroll 4
    for (int it = 0; it < 32; ++it) {
        int c = it * 4 + cb;
        tile[c][pl] = src[c * 16384 + p0 + pl];
    }
    __syncthreads();
    float* dst = out + (long)b * (16384 * 128) + (long)p0 * 128;
    int c  = threadIdx.x & 127;
    int pr = threadIdx.x >> 7;                 // 0..1
#pragma unroll 4
    for (int it = 0; it < 32; ++it) {
        int p = it * 2 + pr;
        dst[p * 128 + c] = tile[c][p];
    }
}

__global__ __launch_bounds__(256) void transpose1_kernel(
    const float* __restrict__ in, float* __restrict__ out)
{
    __shared__ float tile[64][65];
    int b  = blockIdx.x >> 10;
    int p0 = (blockIdx.x & 1023) << 6;
    const float* src = in + (long)b * (64 * 65536);
    int pl = threadIdx.x & 63;
    int cb = threadIdx.x >> 6;
#pragma unroll 4
    for (int it = 0; it < 16; ++it) {
        int c = it * 4 + cb;
        tile[c][pl] = src[c * 65536 + p0 + pl];
    }
    __syncthreads();
    float* dst = out + (long)b * (65536 * 64) + (long)p0 * 64;
    int c2 = threadIdx.x & 63;
    int pr = threadIdx.x >> 6;                 // 0..3
#pragma unroll 4
    for (int it = 0; it < 16; ++it) {
        int p = it * 4 + pr;
        dst[p * 64 + c2] = tile[c2][p];
    }
}

// ---------------- main gathers (channel-contiguous) ----------------

// lv2: wave = 128 channels (float2/lane); 9 coalesced 512B gathers per pixel.
__global__ __launch_bounds__(256) void main2_kernel(
    const float* __restrict__ ws2, const int* __restrict__ hidx,
    float* __restrict__ out)
{
    int wid  = threadIdx.x >> 6;
    int lane = threadIdx.x & 63;
    int pbase = blockIdx.x * 16 + wid * 4;     // 16 consecutive pixels/block
#pragma unroll
    for (int i = 0; i < 4; ++i) {
        int pix = pbase + i;
        int b = pix >> 14;
        int y = (pix >> 7) & 127;
        int x = pix & 127;
        const int*   hb  = hidx + (b << 14);
        const float* src = ws2 + ((long)b << 21);
        float2 acc = make_float2(0.f, 0.f);
#pragma unroll
        for (int da = -1; da <= 1; ++da) {
            int a = y + da;
            if ((unsigned)a >= 128u) continue;
#pragma unroll
            for (int de = -1; de <= 1; ++de) {
                int e = x + de;
                if ((unsigned)e >= 128u) continue;
                int p  = hb[(a << 7) + e];
                int sr = (p >> 7) - da;
                int sc = (p & 127) - de;
                if ((unsigned)sr < 128u && (unsigned)sc < 128u) {
                    float2 v = *(const float2*)(src + ((long)((sr << 7) + sc) << 7) + (lane << 1));
                    acc.x += v.x; acc.y += v.y;
                }
            }
        }
        float* o = out + ((long)(b * 128 + 2 * lane) << 14) + (y << 7) + x;
        o[0]     = acc.x * (1.f / 9.f);
        o[16384] = acc.y * (1.f / 9.f);
    }
}

// lv1: wave = 64 channels (1 float/lane); 2x2 output tile per step;
// 9 patches x (2 rows x 2 px) coalesced 256B gathers.
__global__ __launch_bounds__(256) void main1_kernel(
    const float* __restrict__ ws1, const int* __restrict__ hidx,
    float* __restrict__ out)
{
    int wid  = threadIdx.x >> 6;
    int lane = threadIdx.x & 63;
    int tbase = blockIdx.x * 16 + wid * 4;     // 16 consecutive tiles/block
#pragma unroll
    for (int i = 0; i < 4; ++i) {
        int t  = tbase + i;
        int b  = t >> 14;
        int uy = (t >> 7) & 127;
        int ux = t & 127;
        const int*   hb  = hidx + (b << 14);
        const float* src = ws1 + ((long)b << 22);
        float a00 = 0.f, a01 = 0.f, a10 = 0.f, a11 = 0.f;
#pragma unroll
        for (int ka = 0; ka < 3; ++ka) {
            int jy = uy + 1 - ka;
            if ((unsigned)jy >= 128u) continue;
#pragma unroll
            for (int kb = 0; kb < 3; ++kb) {
                int jx = ux + 1 - kb;
                if ((unsigned)jx >= 128u) continue;
                int p   = hb[(jy << 7) + jx];
                int sr0 = ((p >> 7) << 1) + 2 * ka - 2;   // even, all-or-none valid
                int sc0 = ((p & 127) << 1) + 2 * kb - 2;
                if ((unsigned)sr0 < 256u && (unsigned)sc0 < 256u) {
                    const float* s = src + ((long)((sr0 << 8) + sc0) << 6) + lane;
                    a00 += s[0];
                    a01 += s[64];
                    a10 += s[256 * 64];
                    a11 += s[256 * 64 + 64];
                }
            }
        }
        float* o = out + ((long)(b * 64 + lane) << 16) + (uy << 9) + (ux << 1);
        o[0]   = a00 * (1.f / 9.f);
        o[1]   = a01 * (1.f / 9.f);
        o[256] = a10 * (1.f / 9.f);
        o[257] = a11 * (1.f / 9.f);
    }
}

// ---------------- round-1 fallback (scalar gathers) ----------------

__global__ __launch_bounds__(256) void fb2_kernel(
    const float* __restrict__ lv2, const int* __restrict__ hidx,
    float* __restrict__ out)
{
    int t = blockIdx.x * 256 + threadIdx.x;
    int x  = t & 127;
    int y  = (t >> 7) & 127;
    int bc = t >> 14;
    int b  = t >> 21;
    const int*   hb  = hidx + (b << 14);
    const float* src = lv2 + ((long)bc << 14);
    float acc = 0.f;
#pragma unroll
    for (int da = -1; da <= 1; ++da) {
        int a = y + da;
        if ((unsigned)a >= 128u) continue;
#pragma unroll
        for (int de = -1; de <= 1; ++de) {
            int e = x + de;
            if ((unsigned)e >= 128u) continue;
            int p  = hb[(a << 7) + e];
            int sr = (p >> 7) - da;
            int sc = (p & 127) - de;
            if ((unsigned)sr < 128u && (unsigned)sc < 128u)
                acc += src[(sr << 7) + sc];
        }
    }
    out[t] = acc * (1.f / 9.f);
}

__global__ __launch_bounds__(256) void fb1_kernel(
    const float* __restrict__ lv1, const int* __restrict__ hidx,
    float* __restrict__ out)
{
    int t = blockIdx.x * 256 + threadIdx.x;
    int X  = t & 255;
    int Y  = (t >> 8) & 255;
    int bc = t >> 16;
    int b  = t >> 22;
    const int*   hb  = hidx + (b << 14);
    const float* src = lv1 + ((long)bc << 16);
    int jyh = (Y + 2) >> 1;
    int jxh = (X + 2) >> 1;
    float acc = 0.f;
#pragma unroll
    for (int ka = 0; ka < 3; ++ka) {
        int jy = jyh - ka;
        if ((unsigned)jy >= 128u) continue;
        int dy = Y - 2 * jy;
#pragma unroll
        for (int kb = 0; kb < 3; ++kb) {
            int jx = jxh - kb;
            if ((unsigned)jx >= 128u) continue;
            int dx = X - 2 * jx;
            int p  = hb[(jy << 7) + jx];
            int sr = 2 * (p >> 7) + dy;
            int sc = 2 * (p & 127) + dx;
            if ((unsigned)sr < 256u && (unsigned)sc < 256u)
                acc += src[(sr << 8) + sc];
        }
    }
    out[t] = acc * (1.f / 9.f);
}

extern "C" void kernel_launch(void* const* d_in, const int* in_sizes, int n_in,
                              void* d_out, int out_size, void* d_ws, size_t ws_size,
                              hipStream_t stream)
{
    const float* lv1  = (const float*)d_in[0];
    const float* lv2  = (const float*)d_in[1];
    const int*   hidx = (const int*)d_in[2];
    float* out = (float*)d_out;

    if (ws_size >= WS_NEED) {
        float* ws2 = (float*)d_ws;
        float* ws1 = ws2 + N2ELTS;
        transpose2_kernel<<<512, 256, 0, stream>>>(lv2, ws2);
        transpose1_kernel<<<2048, 256, 0, stream>>>(lv1, ws1);
        main2_kernel<<<2048, 256, 0, stream>>>(ws2, hidx, out);
        main1_kernel<<<2048, 256, 0, stream>>>(ws1, hidx, out + N2ELTS);
    } else {
        fb2_kernel<<<N2ELTS / 256, 256, 0, stream>>>(lv2, hidx, out);
        fb1_kernel<<<N1ELTS / 256, 256, 0, stream>>>(lv1, hidx, out + N2ELTS);
    }
}

// Round 4
// 102.791 us; speedup vs baseline: 5.3079x; 1.4654x over previous
//
#include <hip/hip_runtime.h>

// Compress70, round 4.
// Inputs transposed to channel-innermost (ws2T/ws1T); gathers are coalesced
// wave loads amortized over all channels. This round: (a) unconditional
// MASKED gathers (wave-uniform validity folded into a 0-or-1/9 multiplier,
// clamped addresses) so the compiler keeps all 36 loads in flight;
// (b) readfirstlane on the per-patch index (wave-uniform) -> SGPR addressing;
// (c) channel-contiguous STORES into ws buffers + streaming un-transpose
// (round-3 stores had 4.6x write amplification: lane-stride-256KB scatter).

#define N2 (2*128*128*128)   // 4194304  T_lv2 elements
#define N1 (2*64*256*256)    // 8388608  T_lv1 elements

// ---------------- input transposes: [b][c][p] -> [b][p][c] ----------------

__global__ __launch_bounds__(256) void transpose2_kernel(
    const float* __restrict__ in, float* __restrict__ out)
{
    __shared__ float tile[128][65];
    int b  = blockIdx.x >> 8;
    int p0 = (blockIdx.x & 255) << 6;
    const float* src = in + (long)b * (128 * 16384);
    int pl = threadIdx.x & 63;
    int cb = threadIdx.x >> 6;
#pragma unroll 4
    for (int it = 0; it < 32; ++it) {
        int c = it * 4 + cb;
        tile[c][pl] = src[c * 16384 + p0 + pl];
    }
    __syncthreads();
    float* dst = out + (long)b * (16384 * 128) + (long)p0 * 128;
    int c  = threadIdx.x & 127;
    int pr = threadIdx.x >> 7;
#pragma unroll 4
    for (int it = 0; it < 32; ++it) {
        int p = it * 2 + pr;
        dst[p * 128 + c] = tile[c][p];
    }
}

__global__ __launch_bounds__(256) void transpose1_kernel(
    const float* __restrict__ in, float* __restrict__ out)
{
    __shared__ float tile[64][65];
    int b  = blockIdx.x >> 10;
    int p0 = (blockIdx.x & 1023) << 6;
    const float* src = in + (long)b * (64 * 65536);
    int pl = threadIdx.x & 63;
    int cb = threadIdx.x >> 6;
#pragma unroll 4
    for (int it = 0; it < 16; ++it) {
        int c = it * 4 + cb;
        tile[c][pl] = src[c * 65536 + p0 + pl];
    }
    __syncthreads();
    float* dst = out + (long)b * (65536 * 64) + (long)p0 * 64;
    int c2 = threadIdx.x & 63;
    int pr = threadIdx.x >> 6;
#pragma unroll 4
    for (int it = 0; it < 16; ++it) {
        int p = it * 4 + pr;
        dst[p * 64 + c2] = tile[c2][p];
    }
}

// ---------------- output un-transposes: [b][p][c] -> [b][c][p] -------------

__global__ __launch_bounds__(256) void untranspose2_kernel(
    const float* __restrict__ in, float* __restrict__ out)
{
    __shared__ float tile[128][65];
    int b  = blockIdx.x >> 8;
    int p0 = (blockIdx.x & 255) << 6;
    const float* src = in + ((long)b * 16384 + p0) * 128;
    int c  = threadIdx.x & 127;
    int pr = threadIdx.x >> 7;
#pragma unroll 4
    for (int it = 0; it < 32; ++it) {
        int p = it * 2 + pr;
        tile[c][p] = src[p * 128 + c];
    }
    __syncthreads();
    float* dst = out + (long)b * (128 * 16384);
    int pl = threadIdx.x & 63;
    int cb = threadIdx.x >> 6;
#pragma unroll 4
    for (int it = 0; it < 32; ++it) {
        int cc = it * 4 + cb;
        dst[cc * 16384 + p0 + pl] = tile[cc][pl];
    }
}

__global__ __launch_bounds__(256) void untranspose1_kernel(
    const float* __restrict__ in, float* __restrict__ out)
{
    __shared__ float tile[64][65];
    int b  = blockIdx.x >> 10;
    int p0 = (blockIdx.x & 1023) << 6;
    const float* src = in + ((long)b * 65536 + p0) * 64;
    int c  = threadIdx.x & 63;
    int pr = threadIdx.x >> 6;
#pragma unroll 4
    for (int it = 0; it < 16; ++it) {
        int p = it * 4 + pr;
        tile[c][p] = src[p * 64 + c];
    }
    __syncthreads();
    float* dst = out + (long)b * (64 * 65536);
    int pl = threadIdx.x & 63;
    int cb = threadIdx.x >> 6;
#pragma unroll 4
    for (int it = 0; it < 16; ++it) {
        int cc = it * 4 + cb;
        dst[cc * 65536 + p0 + pl] = tile[cc][pl];
    }
}

// ---------------- main gathers (masked, unconditional, SGPR-indexed) -------

__global__ __launch_bounds__(256) void main2_kernel(
    const float* __restrict__ ws2T, const int* __restrict__ hidx,
    float* __restrict__ ws2O, float* __restrict__ outD, int direct)
{
    int wid  = threadIdx.x >> 6;
    int lane = threadIdx.x & 63;
    int pbase = blockIdx.x * 16 + wid * 4;
#pragma unroll
    for (int i = 0; i < 4; ++i) {
        int pix = pbase + i;
        int b = pix >> 14;
        int y = (pix >> 7) & 127;
        int x = pix & 127;
        const int*   hb  = hidx + (b << 14);
        const float* src = ws2T + ((long)b << 21);
        float accx = 0.f, accy = 0.f;
#pragma unroll
        for (int da = -1; da <= 1; ++da) {
#pragma unroll
            for (int de = -1; de <= 1; ++de) {
                int a = y + da, e = x + de;
                int vj = ((unsigned)a < 128u) & ((unsigned)e < 128u);
                int ia = vj ? ((a << 7) + e) : 0;
                int p  = __builtin_amdgcn_readfirstlane(hb[ia]);
                int sr = (p >> 7) - da;
                int sc = (p & 127) - de;
                int vs = ((unsigned)sr < 128u) & ((unsigned)sc < 128u);
                float msk = (vj & vs) ? (1.f / 9.f) : 0.f;
                long off  = vs ? ((long)((sr << 7) + sc) << 7) : 0;
                float2 v = *(const float2*)(src + off + (lane << 1));
                accx += v.x * msk;
                accy += v.y * msk;
            }
        }
        if (direct) {
            float* o = outD + ((long)(b * 128 + 2 * lane) << 14) + (y << 7) + x;
            o[0]     = accx;
            o[16384] = accy;
        } else {
            float2* o = (float2*)(ws2O + (((long)b * 16384 + (y << 7) + x) << 7) + (lane << 1));
            *o = make_float2(accx, accy);
        }
    }
}

__global__ __launch_bounds__(256) void main1_kernel(
    const float* __restrict__ ws1T, const int* __restrict__ hidx,
    float* __restrict__ ws1O, float* __restrict__ outD, int direct)
{
    int wid  = threadIdx.x >> 6;
    int lane = threadIdx.x & 63;
    int tbase = blockIdx.x * 16 + wid * 4;
#pragma unroll
    for (int i = 0; i < 4; ++i) {
        int t  = tbase + i;
        int b  = t >> 14;
        int uy = (t >> 7) & 127;
        int ux = t & 127;
        const int*   hb  = hidx + (b << 14);
        const float* src = ws1T + ((long)b << 22);
        float a00 = 0.f, a01 = 0.f, a10 = 0.f, a11 = 0.f;
#pragma unroll
        for (int ka = 0; ka < 3; ++ka) {
#pragma unroll
            for (int kb = 0; kb < 3; ++kb) {
                int jy = uy + 1 - ka, jx = ux + 1 - kb;
                int vj = ((unsigned)jy < 128u) & ((unsigned)jx < 128u);
                int ia = vj ? ((jy << 7) + jx) : 0;
                int p  = __builtin_amdgcn_readfirstlane(hb[ia]);
                int sr0 = ((p >> 7) << 1) + 2 * ka - 2;    // even
                int sc0 = ((p & 127) << 1) + 2 * kb - 2;   // even
                int vs  = ((unsigned)sr0 < 256u) & ((unsigned)sc0 < 256u);
                float msk = (vj & vs) ? (1.f / 9.f) : 0.f;
                long off  = vs ? (((long)sr0 << 14) + (sc0 << 6)) : 0;
                const float* s = src + off + lane;
                a00 += s[0]     * msk;
                a01 += s[64]    * msk;
                a10 += s[16384] * msk;
                a11 += s[16448] * msk;
            }
        }
        if (direct) {
            float* o = outD + ((long)(b * 64 + lane) << 16) + (uy << 9) + (ux << 1);
            o[0]   = a00;
            o[1]   = a01;
            o[256] = a10;
            o[257] = a11;
        } else {
            float* o = ws1O + (((long)b * 65536 + (uy << 9) + (ux << 1)) << 6) + lane;
            o[0]     = a00;
            o[64]    = a01;
            o[16384] = a10;
            o[16448] = a11;
        }
    }
}

// ---------------- round-1 scalar fallback ----------------

__global__ __launch_bounds__(256) void fb2_kernel(
    const float* __restrict__ lv2, const int* __restrict__ hidx,
    float* __restrict__ out)
{
    int t = blockIdx.x * 256 + threadIdx.x;
    int x  = t & 127;
    int y  = (t >> 7) & 127;
    int bc = t >> 14;
    int b  = t >> 21;
    const int*   hb  = hidx + (b << 14);
    const float* src = lv2 + ((long)bc << 14);
    float acc = 0.f;
#pragma unroll
    for (int da = -1; da <= 1; ++da) {
        int a = y + da;
        if ((unsigned)a >= 128u) continue;
#pragma unroll
        for (int de = -1; de <= 1; ++de) {
            int e = x + de;
            if ((unsigned)e >= 128u) continue;
            int p  = hb[(a << 7) + e];
            int sr = (p >> 7) - da;
            int sc = (p & 127) - de;
            if ((unsigned)sr < 128u && (unsigned)sc < 128u)
                acc += src[(sr << 7) + sc];
        }
    }
    out[t] = acc * (1.f / 9.f);
}

__global__ __launch_bounds__(256) void fb1_kernel(
    const float* __restrict__ lv1, const int* __restrict__ hidx,
    float* __restrict__ out)
{
    int t = blockIdx.x * 256 + threadIdx.x;
    int X  = t & 255;
    int Y  = (t >> 8) & 255;
    int bc = t >> 16;
    int b  = t >> 22;
    const int*   hb  = hidx + (b << 14);
    const float* src = lv1 + ((long)bc << 16);
    int jyh = (Y + 2) >> 1;
    int jxh = (X + 2) >> 1;
    float acc = 0.f;
#pragma unroll
    for (int ka = 0; ka < 3; ++ka) {
        int jy = jyh - ka;
        if ((unsigned)jy >= 128u) continue;
        int dy = Y - 2 * jy;
#pragma unroll
        for (int kb = 0; kb < 3; ++kb) {
            int jx = jxh - kb;
            if ((unsigned)jx >= 128u) continue;
            int dx = X - 2 * jx;
            int p  = hb[(jy << 7) + jx];
            int sr = 2 * (p >> 7) + dy;
            int sc = 2 * (p & 127) + dx;
            if ((unsigned)sr < 256u && (unsigned)sc < 256u)
                acc += src[(sr << 8) + sc];
        }
    }
    out[t] = acc * (1.f / 9.f);
}

extern "C" void kernel_launch(void* const* d_in, const int* in_sizes, int n_in,
                              void* d_out, int out_size, void* d_ws, size_t ws_size,
                              hipStream_t stream)
{
    const float* lv1  = (const float*)d_in[0];
    const float* lv2  = (const float*)d_in[1];
    const int*   hidx = (const int*)d_in[2];
    float* out = (float*)d_out;

    size_t need_full = (size_t)(N2 + N1) * 2 * 4;   // ~100.7 MB
    size_t need_half = (size_t)(N2 + N1) * 4;       // ~50.3 MB

    if (ws_size >= need_half) {
        float* ws2T = (float*)d_ws;
        float* ws1T = ws2T + N2;
        int full = ws_size >= need_full;
        float* ws2O = full ? (ws1T + N1) : nullptr;
        float* ws1O = full ? (ws1T + N1 + N2) : nullptr;

        transpose2_kernel<<<512, 256, 0, stream>>>(lv2, ws2T);
        transpose1_kernel<<<2048, 256, 0, stream>>>(lv1, ws1T);
        main2_kernel<<<2048, 256, 0, stream>>>(ws2T, hidx, ws2O, out, !full);
        main1_kernel<<<2048, 256, 0, stream>>>(ws1T, hidx, ws1O, out + N2, !full);
        if (full) {
            untranspose2_kernel<<<512, 256, 0, stream>>>(ws2O, out);
            untranspose1_kernel<<<2048, 256, 0, stream>>>(ws1O, out + N2);
        }
    } else {
        fb2_kernel<<<N2 / 256, 256, 0, stream>>>(lv2, hidx, out);
        fb1_kernel<<<N1 / 256, 256, 0, stream>>>(lv1, hidx, out + N2);
    }
}

// Round 5
// 81.448 us; speedup vs baseline: 6.6989x; 1.2621x over previous
//
#include <hip/hip_runtime.h>

// Compress70, round 5.
// - ws1T in 2x2-blocked layout: BL1(b,sy,sx,c) = (b<<22)+((sy>>1)<<15)+((sx>>1)<<8)
//   +(c<<2)+((sy&1)<<1)+(sx&1). Patch coords (sr0,sc0) are always even ->
//   one float4 wave-load per patch (was 4 float loads).
// - XCD-chunked bijective block swizzle on main kernels: each XCD's L2 sees a
//   contiguous output chunk whose random-patch footprint (~3.8MB) fits 4MB L2.
// - Output un-transpose fused into main kernels via padded LDS staging
//   (coalesced channel-major stores; no ws round-trip).

#define N2 (2*128*128*128)   // 4194304
#define N1 (2*64*256*256)    // 8388608
#define WS_NEED ((size_t)(N2 + N1) * 4)

// ---------- transpose2: lv2 [b][c][p] -> ws2T [b][p][128c] ----------
__global__ __launch_bounds__(256) void transpose2_kernel(
    const float* __restrict__ in, float* __restrict__ out)
{
    __shared__ float tile[128][65];
    int b  = blockIdx.x >> 8;
    int p0 = (blockIdx.x & 255) << 6;
    const float* src = in + (long)b * (128 * 16384);
    int pl = threadIdx.x & 63;
    int cb = threadIdx.x >> 6;
#pragma unroll 4
    for (int it = 0; it < 32; ++it) {
        int c = it * 4 + cb;
        tile[c][pl] = src[c * 16384 + p0 + pl];
    }
    __syncthreads();
    float* dst = out + (long)b * (16384 * 128) + (long)p0 * 128;
    int c  = threadIdx.x & 127;
    int pr = threadIdx.x >> 7;
#pragma unroll 4
    for (int it = 0; it < 32; ++it) {
        int p = it * 2 + pr;
        dst[p * 128 + c] = tile[c][p];
    }
}

// ---------- transpose1: lv1 [b][c][sy][sx] -> ws1T blocked BL1 ----------
__global__ __launch_bounds__(256) void transpose1b_kernel(
    const float* __restrict__ in, float* __restrict__ out)
{
    __shared__ float lds[2 * 64 * 65];
    int bid = blockIdx.x;                 // ((b*128+sy2)*4+sxc)
    int sxc = bid & 3;
    int sy2 = (bid >> 2) & 127;
    int b   = bid >> 9;
    int lane = threadIdx.x & 63;
    int wid  = threadIdx.x >> 6;
    const float* src = in + ((long)b << 22);
    int sy0 = sy2 * 2, sx0 = sxc * 64;
#pragma unroll 4
    for (int it = 0; it < 32; ++it) {
        int row = it * 4 + wid;           // 0..127 -> (c, r)
        int c = row >> 1, r = row & 1;
        float v = src[((long)c << 16) + ((sy0 + r) << 8) + sx0 + lane];
        lds[(r * 64 + lane) * 65 + c] = v;
    }
    __syncthreads();
    float* dst = out + ((long)b << 22) + ((long)sy2 << 15) + (sxc << 13);
#pragma unroll
    for (int it = 0; it < 8; ++it) {
        int g = it * 4 + wid;             // 0..31 (sx pair)
        float4 v;
        v.x = lds[(2 * g) * 65 + lane];
        v.y = lds[(2 * g + 1) * 65 + lane];
        v.z = lds[(64 + 2 * g) * 65 + lane];
        v.w = lds[(64 + 2 * g + 1) * 65 + lane];
        *(float4*)(dst + (g << 8) + (lane << 2)) = v;
    }
}

// ---------- main1: 1 float4 gather per patch; fused transposed store -------
__global__ __launch_bounds__(256) void main1_kernel(
    const float* __restrict__ ws1T, const int* __restrict__ hidx,
    float* __restrict__ out1)
{
    __shared__ float lds[2 * 64 * 65];    // [r][X][c] padded
    int wb   = (blockIdx.x & 7) * 128 + (blockIdx.x >> 3);  // 1024 blocks
    int lane = threadIdx.x & 63;
    int wave = threadIdx.x >> 6;
    int t0  = wb * 32;                    // 32 consecutive tiles, same (b,uy)
    int b   = t0 >> 14;
    int uy  = (t0 >> 7) & 127;
    int ux0 = t0 & 127;
    const int*   hb  = hidx + (b << 14);
    const float* src = ws1T + ((long)b << 22);
#pragma unroll
    for (int i = 0; i < 8; ++i) {
        int ti = wave * 8 + i;
        int ux = ux0 + ti;
        float4 acc = make_float4(0.f, 0.f, 0.f, 0.f);
#pragma unroll
        for (int ka = 0; ka < 3; ++ka) {
#pragma unroll
            for (int kb = 0; kb < 3; ++kb) {
                int jy = uy + 1 - ka, jx = ux + 1 - kb;
                int vj = ((unsigned)jy < 128u) & ((unsigned)jx < 128u);
                int ia = vj ? ((jy << 7) + jx) : 0;
                int p  = __builtin_amdgcn_readfirstlane(hb[ia]);
                int ry = (p >> 7) + ka - 1;     // sr0>>1
                int rx = (p & 127) + kb - 1;    // sc0>>1
                int vs = ((unsigned)ry < 128u) & ((unsigned)rx < 128u);
                float msk = (vj & vs) ? (1.f / 9.f) : 0.f;
                int off = vs ? ((ry << 15) + (rx << 8)) : 0;
                float4 v = *(const float4*)(src + off + (lane << 2));
                acc.x += v.x * msk; acc.y += v.y * msk;
                acc.z += v.z * msk; acc.w += v.w * msk;
            }
        }
        int X = ti * 2;
        lds[(X) * 65 + lane]          = acc.x;   // (Y0,   X)
        lds[(X + 1) * 65 + lane]      = acc.y;   // (Y0,   X+1)
        lds[(64 + X) * 65 + lane]     = acc.z;   // (Y0+1, X)
        lds[(64 + X + 1) * 65 + lane] = acc.w;   // (Y0+1, X+1)
    }
    __syncthreads();
    int Y0 = uy * 2, X0 = ux0 * 2;
    float* dst = out1 + ((long)b << 22);
#pragma unroll 4
    for (int it = 0; it < 32; ++it) {
        int row = it * 4 + wave;          // 0..127 -> (c, r)
        int c = row >> 1, r = row & 1;
        dst[((long)c << 16) + ((Y0 + r) << 8) + X0 + lane] =
            lds[(r * 64 + lane) * 65 + c];
    }
}

// ---------- main2: float2 gathers; fused transposed store ----------
__global__ __launch_bounds__(256) void main2_kernel(
    const float* __restrict__ ws2T, const int* __restrict__ hidx,
    float* __restrict__ out)
{
    __shared__ float lds[64 * 129];       // [X][c] padded
    int wb   = (blockIdx.x & 7) * 64 + (blockIdx.x >> 3);   // 512 blocks
    int lane = threadIdx.x & 63;
    int wave = threadIdx.x >> 6;
    int p0 = wb * 64;                     // 64 consecutive pixels, same (b,y)
    int b  = p0 >> 14;
    int y  = (p0 >> 7) & 127;
    int x0 = p0 & 127;
    const int*   hb  = hidx + (b << 14);
    const float* src = ws2T + ((long)b << 21);
#pragma unroll
    for (int i = 0; i < 16; ++i) {
        int Xl = wave * 16 + i;
        int x  = x0 + Xl;
        float ax = 0.f, ay = 0.f;
#pragma unroll
        for (int da = -1; da <= 1; ++da) {
#pragma unroll
            for (int de = -1; de <= 1; ++de) {
                int a = y + da, e = x + de;
                int vj = ((unsigned)a < 128u) & ((unsigned)e < 128u);
                int ia = vj ? ((a << 7) + e) : 0;
                int p  = __builtin_amdgcn_readfirstlane(hb[ia]);
                int sr = (p >> 7) - da;
                int sc = (p & 127) - de;
                int vs = ((unsigned)sr < 128u) & ((unsigned)sc < 128u);
                float msk = (vj & vs) ? (1.f / 9.f) : 0.f;
                int off = vs ? (((sr << 7) + sc) << 7) : 0;
                float2 v = *(const float2*)(src + off + (lane << 1));
                ax += v.x * msk; ay += v.y * msk;
            }
        }
        lds[Xl * 129 + 2 * lane]     = ax;
        lds[Xl * 129 + 2 * lane + 1] = ay;
    }
    __syncthreads();
#pragma unroll 4
    for (int it = 0; it < 32; ++it) {
        int c = it * 4 + wave;            // 0..127
        out[((long)(b * 128 + c) << 14) + (y << 7) + x0 + lane] =
            lds[lane * 129 + c];
    }
}

// ---------- round-1 scalar fallback ----------
__global__ __launch_bounds__(256) void fb2_kernel(
    const float* __restrict__ lv2, const int* __restrict__ hidx,
    float* __restrict__ out)
{
    int t = blockIdx.x * 256 + threadIdx.x;
    int x  = t & 127;
    int y  = (t >> 7) & 127;
    int bc = t >> 14;
    int b  = t >> 21;
    const int*   hb  = hidx + (b << 14);
    const float* src = lv2 + ((long)bc << 14);
    float acc = 0.f;
#pragma unroll
    for (int da = -1; da <= 1; ++da) {
        int a = y + da;
        if ((unsigned)a >= 128u) continue;
#pragma unroll
        for (int de = -1; de <= 1; ++de) {
            int e = x + de;
            if ((unsigned)e >= 128u) continue;
            int p  = hb[(a << 7) + e];
            int sr = (p >> 7) - da;
            int sc = (p & 127) - de;
            if ((unsigned)sr < 128u && (unsigned)sc < 128u)
                acc += src[(sr << 7) + sc];
        }
    }
    out[t] = acc * (1.f / 9.f);
}

__global__ __launch_bounds__(256) void fb1_kernel(
    const float* __restrict__ lv1, const int* __restrict__ hidx,
    float* __restrict__ out)
{
    int t = blockIdx.x * 256 + threadIdx.x;
    int X  = t & 255;
    int Y  = (t >> 8) & 255;
    int bc = t >> 16;
    int b  = t >> 22;
    const int*   hb  = hidx + (b << 14);
    const float* src = lv1 + ((long)bc << 16);
    int jyh = (Y + 2) >> 1;
    int jxh = (X + 2) >> 1;
    float acc = 0.f;
#pragma unroll
    for (int ka = 0; ka < 3; ++ka) {
        int jy = jyh - ka;
        if ((unsigned)jy >= 128u) continue;
        int dy = Y - 2 * jy;
#pragma unroll
        for (int kb = 0; kb < 3; ++kb) {
            int jx = jxh - kb;
            if ((unsigned)jx >= 128u) continue;
            int dx = X - 2 * jx;
            int p  = hb[(jy << 7) + jx];
            int sr = 2 * (p >> 7) + dy;
            int sc = 2 * (p & 127) + dx;
            if ((unsigned)sr < 256u && (unsigned)sc < 256u)
                acc += src[(sr << 8) + sc];
        }
    }
    out[t] = acc * (1.f / 9.f);
}

extern "C" void kernel_launch(void* const* d_in, const int* in_sizes, int n_in,
                              void* d_out, int out_size, void* d_ws, size_t ws_size,
                              hipStream_t stream)
{
    const float* lv1  = (const float*)d_in[0];
    const float* lv2  = (const float*)d_in[1];
    const int*   hidx = (const int*)d_in[2];
    float* out = (float*)d_out;

    if (ws_size >= WS_NEED) {
        float* ws2T = (float*)d_ws;
        float* ws1T = ws2T + N2;
        transpose2_kernel<<<512, 256, 0, stream>>>(lv2, ws2T);
        transpose1b_kernel<<<1024, 256, 0, stream>>>(lv1, ws1T);
        main2_kernel<<<512, 256, 0, stream>>>(ws2T, hidx, out);
        main1_kernel<<<1024, 256, 0, stream>>>(ws1T, hidx, out + N2);
    } else {
        fb2_kernel<<<N2 / 256, 256, 0, stream>>>(lv2, hidx, out);
        fb1_kernel<<<N1 / 256, 256, 0, stream>>>(lv1, hidx, out + N2);
    }
}

// Round 6
// 76.172 us; speedup vs baseline: 7.1628x; 1.0693x over previous
//
#include <hip/hip_runtime.h>

// Compress70, round 6.
// Structure as round 5 (transposed channel-innermost inputs, 2x2-blocked ws1T,
// masked SGPR-uniform gathers, fused LDS un-transpose stores) with:
//  - explicit pairwise load arrays (18 gathers in flight per wave) -> MLP;
//  - main1+main2 fused into one dispatch, transposes fused into one dispatch;
//  - chunked-bijective XCD swizzle on the mains grid (1536 % 8 == 0).

#define N2 (2*128*128*128)   // 4194304
#define N1 (2*64*256*256)    // 8388608
#define WS_NEED ((size_t)(N2 + N1) * 4)

// ---------------- fused input transposes ----------------
__global__ __launch_bounds__(256) void prep_kernel(
    const float* __restrict__ lv1, const float* __restrict__ lv2,
    float* __restrict__ ws2T, float* __restrict__ ws1T)
{
    __shared__ float lds[8320];
    int bid  = blockIdx.x;
    int lane = threadIdx.x & 63;
    int wid  = threadIdx.x >> 6;
    if (bid < 512) {
        // lv2 [b][c][p] -> ws2T [b][p][128c]
        int b  = bid >> 8;
        int p0 = (bid & 255) << 6;
        const float* src = lv2 + (long)b * (128 * 16384);
#pragma unroll 4
        for (int it = 0; it < 32; ++it) {
            int c = it * 4 + wid;
            lds[c * 65 + lane] = src[c * 16384 + p0 + lane];
        }
        __syncthreads();
        float* dst = ws2T + (long)b * (16384 * 128) + (long)p0 * 128;
        int c  = threadIdx.x & 127;
        int pr = threadIdx.x >> 7;
#pragma unroll 4
        for (int it = 0; it < 32; ++it) {
            int p = it * 2 + pr;
            dst[p * 128 + c] = lds[c * 65 + p];
        }
    } else {
        // lv1 [b][c][sy][sx] -> ws1T blocked: (b<<22)+((sy>>1)<<15)+((sx>>1)<<8)+(c<<2)+((sy&1)<<1)+(sx&1)
        int bb  = bid - 512;
        int sxc = bb & 3;
        int sy2 = (bb >> 2) & 127;
        int b   = bb >> 9;
        const float* src = lv1 + ((long)b << 22);
        int sy0 = sy2 * 2, sx0 = sxc * 64;
#pragma unroll 4
        for (int it = 0; it < 32; ++it) {
            int row = it * 4 + wid;       // (c, r)
            int c = row >> 1, r = row & 1;
            lds[(r * 64 + lane) * 65 + c] =
                src[((long)c << 16) + ((sy0 + r) << 8) + sx0 + lane];
        }
        __syncthreads();
        float* dst = ws1T + ((long)b << 22) + ((long)sy2 << 15) + (sxc << 13);
#pragma unroll
        for (int it = 0; it < 8; ++it) {
            int g = it * 4 + wid;
            float4 v;
            v.x = lds[(2 * g) * 65 + lane];
            v.y = lds[(2 * g + 1) * 65 + lane];
            v.z = lds[(64 + 2 * g) * 65 + lane];
            v.w = lds[(64 + 2 * g + 1) * 65 + lane];
            *(float4*)(dst + (g << 8) + (lane << 2)) = v;
        }
    }
}

// ---------------- fused main gathers ----------------
__global__ __launch_bounds__(256) void mains_kernel(
    const float* __restrict__ ws2T, const float* __restrict__ ws1T,
    const int* __restrict__ hidx, float* __restrict__ out)
{
    __shared__ float lds[8320];
    int bid  = blockIdx.x;
    int wid_all = (bid & 7) * 192 + (bid >> 3);   // bijective, XCD-chunked
    int lane = threadIdx.x & 63;
    int wave = threadIdx.x >> 6;

    if (wid_all < 512) {
        // ---- main2: 64 consecutive pixels (one b,y row segment) ----
        int p0 = wid_all * 64;
        int b  = p0 >> 14;
        int y  = (p0 >> 7) & 127;
        int x0 = p0 & 127;
        const int*   hb  = hidx + (b << 14);
        const float* src = ws2T + ((long)b << 21);
        int lane2 = lane << 1;
#pragma unroll
        for (int ii = 0; ii < 8; ++ii) {
            int XlA = (wave << 4) + (ii << 1);
            int xA  = x0 + XlA;
            float2 vA[9], vB[9];
            float  mA[9], mB[9];
#pragma unroll
            for (int da = -1; da <= 1; ++da) {
#pragma unroll
                for (int de = -1; de <= 1; ++de) {
                    int k = (da + 1) * 3 + (de + 1);
                    {
                        int a = y + da, e = xA + de;
                        int vj = ((unsigned)a < 128u) & ((unsigned)e < 128u);
                        int ia = __builtin_amdgcn_readfirstlane(vj ? ((a << 7) + e) : 0);
                        int p  = __builtin_amdgcn_readfirstlane(hb[ia]);
                        int sr = (p >> 7) - da, sc = (p & 127) - de;
                        int vs = ((unsigned)sr < 128u) & ((unsigned)sc < 128u);
                        mA[k] = (vj & vs) ? (1.f / 9.f) : 0.f;
                        vA[k] = *(const float2*)(src + (vs ? (((sr << 7) + sc) << 7) : 0) + lane2);
                    }
                    {
                        int a = y + da, e = xA + 1 + de;
                        int vj = ((unsigned)a < 128u) & ((unsigned)e < 128u);
                        int ia = __builtin_amdgcn_readfirstlane(vj ? ((a << 7) + e) : 0);
                        int p  = __builtin_amdgcn_readfirstlane(hb[ia]);
                        int sr = (p >> 7) - da, sc = (p & 127) - de;
                        int vs = ((unsigned)sr < 128u) & ((unsigned)sc < 128u);
                        mB[k] = (vj & vs) ? (1.f / 9.f) : 0.f;
                        vB[k] = *(const float2*)(src + (vs ? (((sr << 7) + sc) << 7) : 0) + lane2);
                    }
                }
            }
            float axA = 0.f, ayA = 0.f, axB = 0.f, ayB = 0.f;
#pragma unroll
            for (int k = 0; k < 9; ++k) {
                axA += vA[k].x * mA[k]; ayA += vA[k].y * mA[k];
                axB += vB[k].x * mB[k]; ayB += vB[k].y * mB[k];
            }
            lds[XlA * 129 + lane2]           = axA;
            lds[XlA * 129 + lane2 + 1]       = ayA;
            lds[(XlA + 1) * 129 + lane2]     = axB;
            lds[(XlA + 1) * 129 + lane2 + 1] = ayB;
        }
        __syncthreads();
#pragma unroll 4
        for (int it = 0; it < 32; ++it) {
            int c = it * 4 + wave;
            out[((long)(b * 128 + c) << 14) + (y << 7) + x0 + lane] =
                lds[lane * 129 + c];
        }
    } else {
        // ---- main1: 32 consecutive 2x2 tiles (one b,uy row segment) ----
        int w1  = wid_all - 512;
        int t0  = w1 * 32;
        int b   = t0 >> 14;
        int uy  = (t0 >> 7) & 127;
        int ux0 = t0 & 127;
        const int*   hb  = hidx + (b << 14);
        const float* src = ws1T + ((long)b << 22);
        float* out1 = out + N2;
        int lane4 = lane << 2;
#pragma unroll
        for (int ii = 0; ii < 4; ++ii) {
            int tiA = (wave << 3) + (ii << 1);
            int uxA = ux0 + tiA;
            float4 vA[9], vB[9];
            float  mA[9], mB[9];
#pragma unroll
            for (int ka = 0; ka < 3; ++ka) {
#pragma unroll
                for (int kb = 0; kb < 3; ++kb) {
                    int k = ka * 3 + kb;
                    {
                        int jy = uy + 1 - ka, jx = uxA + 1 - kb;
                        int vj = ((unsigned)jy < 128u) & ((unsigned)jx < 128u);
                        int ia = __builtin_amdgcn_readfirstlane(vj ? ((jy << 7) + jx) : 0);
                        int p  = __builtin_amdgcn_readfirstlane(hb[ia]);
                        int ry = (p >> 7) + ka - 1, rx = (p & 127) + kb - 1;
                        int vs = ((unsigned)ry < 128u) & ((unsigned)rx < 128u);
                        mA[k] = (vj & vs) ? (1.f / 9.f) : 0.f;
                        vA[k] = *(const float4*)(src + (vs ? ((ry << 15) + (rx << 8)) : 0) + lane4);
                    }
                    {
                        int jy = uy + 1 - ka, jx = uxA + 2 - kb;
                        int vj = ((unsigned)jy < 128u) & ((unsigned)jx < 128u);
                        int ia = __builtin_amdgcn_readfirstlane(vj ? ((jy << 7) + jx) : 0);
                        int p  = __builtin_amdgcn_readfirstlane(hb[ia]);
                        int ry = (p >> 7) + ka - 1, rx = (p & 127) + kb - 1;
                        int vs = ((unsigned)ry < 128u) & ((unsigned)rx < 128u);
                        mB[k] = (vj & vs) ? (1.f / 9.f) : 0.f;
                        vB[k] = *(const float4*)(src + (vs ? ((ry << 15) + (rx << 8)) : 0) + lane4);
                    }
                }
            }
            float4 aA = make_float4(0.f, 0.f, 0.f, 0.f);
            float4 aB = make_float4(0.f, 0.f, 0.f, 0.f);
#pragma unroll
            for (int k = 0; k < 9; ++k) {
                aA.x += vA[k].x * mA[k]; aA.y += vA[k].y * mA[k];
                aA.z += vA[k].z * mA[k]; aA.w += vA[k].w * mA[k];
                aB.x += vB[k].x * mB[k]; aB.y += vB[k].y * mB[k];
                aB.z += vB[k].z * mB[k]; aB.w += vB[k].w * mB[k];
            }
            int XA = tiA * 2;
            lds[(XA) * 65 + lane]          = aA.x;
            lds[(XA + 1) * 65 + lane]      = aA.y;
            lds[(64 + XA) * 65 + lane]     = aA.z;
            lds[(64 + XA + 1) * 65 + lane] = aA.w;
            lds[(XA + 2) * 65 + lane]      = aB.x;
            lds[(XA + 3) * 65 + lane]      = aB.y;
            lds[(64 + XA + 2) * 65 + lane] = aB.z;
            lds[(64 + XA + 3) * 65 + lane] = aB.w;
        }
        __syncthreads();
        int Y0 = uy * 2, X0 = ux0 * 2;
        float* dst = out1 + ((long)b << 22);
#pragma unroll 4
        for (int it = 0; it < 32; ++it) {
            int row = it * 4 + wave;      // (c, r)
            int c = row >> 1, r = row & 1;
            dst[((long)c << 16) + ((Y0 + r) << 8) + X0 + lane] =
                lds[(r * 64 + lane) * 65 + c];
        }
    }
}

// ---------------- round-1 scalar fallback ----------------
__global__ __launch_bounds__(256) void fb2_kernel(
    const float* __restrict__ lv2, const int* __restrict__ hidx,
    float* __restrict__ out)
{
    int t = blockIdx.x * 256 + threadIdx.x;
    int x  = t & 127;
    int y  = (t >> 7) & 127;
    int bc = t >> 14;
    int b  = t >> 21;
    const int*   hb  = hidx + (b << 14);
    const float* src = lv2 + ((long)bc << 14);
    float acc = 0.f;
#pragma unroll
    for (int da = -1; da <= 1; ++da) {
        int a = y + da;
        if ((unsigned)a >= 128u) continue;
#pragma unroll
        for (int de = -1; de <= 1; ++de) {
            int e = x + de;
            if ((unsigned)e >= 128u) continue;
            int p  = hb[(a << 7) + e];
            int sr = (p >> 7) - da;
            int sc = (p & 127) - de;
            if ((unsigned)sr < 128u && (unsigned)sc < 128u)
                acc += src[(sr << 7) + sc];
        }
    }
    out[t] = acc * (1.f / 9.f);
}

__global__ __launch_bounds__(256) void fb1_kernel(
    const float* __restrict__ lv1, const int* __restrict__ hidx,
    float* __restrict__ out)
{
    int t = blockIdx.x * 256 + threadIdx.x;
    int X  = t & 255;
    int Y  = (t >> 8) & 255;
    int bc = t >> 16;
    int b  = t >> 22;
    const int*   hb  = hidx + (b << 14);
    const float* src = lv1 + ((long)bc << 16);
    int jyh = (Y + 2) >> 1;
    int jxh = (X + 2) >> 1;
    float acc = 0.f;
#pragma unroll
    for (int ka = 0; ka < 3; ++ka) {
        int jy = jyh - ka;
        if ((unsigned)jy >= 128u) continue;
        int dy = Y - 2 * jy;
#pragma unroll
        for (int kb = 0; kb < 3; ++kb) {
            int jx = jxh - kb;
            if ((unsigned)jx >= 128u) continue;
            int dx = X - 2 * jx;
            int p  = hb[(jy << 7) + jx];
            int sr = 2 * (p >> 7) + dy;
            int sc = 2 * (p & 127) + dx;
            if ((unsigned)sr < 256u && (unsigned)sc < 256u)
                acc += src[(sr << 8) + sc];
        }
    }
    out[t] = acc * (1.f / 9.f);
}

extern "C" void kernel_launch(void* const* d_in, const int* in_sizes, int n_in,
                              void* d_out, int out_size, void* d_ws, size_t ws_size,
                              hipStream_t stream)
{
    const float* lv1  = (const float*)d_in[0];
    const float* lv2  = (const float*)d_in[1];
    const int*   hidx = (const int*)d_in[2];
    float* out = (float*)d_out;

    if (ws_size >= WS_NEED) {
        float* ws2T = (float*)d_ws;
        float* ws1T = ws2T + N2;
        prep_kernel<<<1536, 256, 0, stream>>>(lv1, lv2, ws2T, ws1T);
        mains_kernel<<<1536, 256, 0, stream>>>(ws2T, ws1T, hidx, out);
    } else {
        fb2_kernel<<<N2 / 256, 256, 0, stream>>>(lv2, hidx, out);
        fb1_kernel<<<N1 / 256, 256, 0, stream>>>(lv1, hidx, out + N2);
    }
}